// Round 3
// baseline (1170.382 us; speedup 1.0000x reference)
//
#include <hip/hip_runtime.h>
#include <hip/hip_bf16.h>

// Viterbi CRF decode: B=512, T=512, K=64.
// Round 3:
//  fwd: 1 wave/batch, sync-free. All 64 prev-tag scores read via v_readlane
//    (wave-uniform SGPRs), trans column in 64 VGPRs. No LDS, no barriers in
//    the t-loop -> pure issue-bound (~820 cyc/step). fp association
//    (score+trans)+emit exact; 4 strict-> chains (ascending i) merged
//    ascending = jnp.argmax first-index tie rule. Bitwise-exact vs reference.
//  bt: hypothesis-parallel chase. 4 waves/block stage 32KB hist in LDS; wave
//    w chases chunks {w,w+4} with all 64 entry hypotheses in parallel (lane j
//    = hypothesis j), recording packed path bytes in registers. Dependent-
//    load chain 511 -> 128 hops. 8-map composition + shuffle-broadcast emit.
// Workspace: hist uint8 [B][512][K] (row 511 pad) + best_last int[B].

#define TT 512
#define BB 512
#define KK 64

#define NEG_INF (-3.402823466e38f)

__device__ __forceinline__ float rl(float v, int lane) {
    return __uint_as_float(__builtin_amdgcn_readlane(__float_as_uint(v), lane));
}

__global__ __launch_bounds__(64) void viterbi_fwd(
    const float* __restrict__ emissions,   // [B,T,K]
    const int* __restrict__ attn_mask,     // [B,T]
    const float* __restrict__ start_t,     // [K]
    const float* __restrict__ end_t,       // [K]
    const float* __restrict__ trans,       // [K,K]
    unsigned char* __restrict__ hist,      // [B,512,K] (row 511 pad)
    int* __restrict__ best_last)           // [B]
{
    const int b = blockIdx.x;
    const int j = threadIdx.x;

    // trans column j in registers: tc[i] = trans[i][j]
    float tc[KK];
#pragma unroll
    for (int i = 0; i < KK; ++i) tc[i] = trans[i * KK + j];

    const float* eb = emissions + (size_t)b * TT * KK;
    const int*   mb = attn_mask + (size_t)b * TT;
    unsigned char* hb = hist + (size_t)b * TT * KK;

    float score = start_t[j] + eb[j];

    // 2-deep prefetch rings
    float e0 = eb[KK + j];
    float e1 = eb[2 * KK + j];
    int   m0 = mb[1];
    int   m1 = mb[2];

    for (int t = 1; t < TT; ++t) {
        float e = e0; e0 = e1;
        int   m = m0; m0 = m1;
        int tn = (t + 2 < TT) ? (t + 2) : (TT - 1);
        e1 = eb[(size_t)tn * KK + j];
        m1 = mb[tn];

        // 4 strict-> chains over ascending i, merged ascending:
        // reproduces jnp.argmax first-index tie-break exactly.
        float bbv[4]; int bbi[4];
#pragma unroll
        for (int c = 0; c < 4; ++c) { bbv[c] = NEG_INF; bbi[c] = c * 16; }
#pragma unroll
        for (int c = 0; c < 4; ++c) {
#pragma unroll
            for (int q = 0; q < 16; ++q) {
                const int idx = c * 16 + q;
                float s = rl(score, idx);
                float cand = (s + tc[idx]) + e;   // exact reference association
                if (cand > bbv[c]) { bbv[c] = cand; bbi[c] = idx; }
            }
        }
        float best = bbv[0]; int bi = bbi[0];
        if (bbv[1] > best) { best = bbv[1]; bi = bbi[1]; }
        if (bbv[2] > best) { best = bbv[2]; bi = bbi[2]; }
        if (bbv[3] > best) { best = bbv[3]; bi = bbi[3]; }

        hb[(size_t)(t - 1) * KK + j] = (unsigned char)bi;
        score = m ? best : score;   // freeze past sequence end
    }

    // final argmax (uniform on all lanes via readlane; lane 0 stores)
    float fin = score + end_t[j];
    float bv = rl(fin, 0); int bt_ = 0;
#pragma unroll
    for (int k = 1; k < KK; ++k) {
        float v = rl(fin, k);
        if (v > bv) { bv = v; bt_ = k; }
    }
    if (j == 0) best_last[b] = bt_;
}

__global__ __launch_bounds__(256) void viterbi_bt(
    const unsigned char* __restrict__ hist,  // [B,512,K]
    const int* __restrict__ attn_mask,       // [B,T]
    const int* __restrict__ best_last,       // [B]
    int* __restrict__ out)                   // [B,T] int32
{
    const int b   = blockIdx.x;
    const int tid = threadIdx.x;
    const int w   = __builtin_amdgcn_readfirstlane(tid >> 6);  // wave id
    const int l   = tid & 63;

    __shared__ unsigned char sh[TT * KK];    // 32 KB hist block
    __shared__ unsigned char maps[8][KK];    // chunk exit maps
    __shared__ int entries[8];

    // cooperative coalesced staging: 2048 uint4 over 256 lanes
    {
        const uint4* hw4 = (const uint4*)(hist + (size_t)b * TT * KK);
        uint4* sh4 = (uint4*)sh;
#pragma unroll
        for (int k = 0; k < 8; ++k) sh4[tid + k * 256] = hw4[tid + k * 256];
    }
    const int* mb = attn_mask + (size_t)b * TT;
    __syncthreads();

    // hypothesis-parallel chase: wave w handles chunks c = w, w+4.
    // lane l chases entry hypothesis tag=l through the chunk, recording the
    // path bytes packed 4-per-dword in registers.
    unsigned int rec_reg[2][16];
#pragma unroll
    for (int cc = 0; cc < 2; ++cc) {
        const int c = w + cc * 4;
        // mask bits for rows r = c*64 + i (row r uses attn_mask[b][r+1])
        int r_l = c * KK + l;
        int mreg = (r_l <= TT - 2) ? mb[r_l + 1] : 0;
        unsigned long long mb64 = __ballot(mreg != 0);

        int tag = l;
#pragma unroll
        for (int k = 0; k < 16; ++k) rec_reg[cc][k] = 0;
#pragma unroll
        for (int i = 63; i >= 0; --i) {
            // hist[r][tag], r = c*64+i (row 511 read is dead, mask bit = 0)
            int v = (int)sh[c * 4096 + i * KK + tag];
            int mbit = (int)((mb64 >> i) & 1ull);   // wave-uniform
            tag = mbit ? v : tag;
            rec_reg[cc][i >> 2] |= (unsigned int)tag << ((i & 3) * 8);
        }
        maps[c][l] = (unsigned char)tag;   // chunk exit for hypothesis l
    }
    __syncthreads();

    // compose the 8 chunk maps (serial, tiny)
    if (tid == 0) {
        int tg = best_last[b];
        for (int c = 7; c >= 0; --c) {
            entries[c] = tg;        // true entry tag for chunk c
            tg = maps[c][tg];       // exit becomes entry of chunk c-1
        }
    }
    __syncthreads();

    // emit: broadcast the winning lane's record via 16 uniform shuffles
#pragma unroll
    for (int cc = 0; cc < 2; ++cc) {
        const int c = w + cc * 4;
        const int e = entries[c];
        unsigned int myd = 0;
#pragma unroll
        for (int k = 0; k < 16; ++k) {
            unsigned int dv = (unsigned int)__shfl((int)rec_reg[cc][k], e);
            if ((l >> 2) == k) myd = dv;
        }
        int v = (int)((myd >> ((l & 3) * 8)) & 0xFFu);
        out[(size_t)b * TT + c * KK + l] = v;
    }
}

extern "C" void kernel_launch(void* const* d_in, const int* in_sizes, int n_in,
                              void* d_out, int out_size, void* d_ws, size_t ws_size,
                              hipStream_t stream) {
    const float* emissions = (const float*)d_in[0];
    const int* attn_mask   = (const int*)d_in[1];
    const float* start_t   = (const float*)d_in[2];
    const float* end_t     = (const float*)d_in[3];
    const float* trans     = (const float*)d_in[4];
    int* out = (int*)d_out;

    unsigned char* hist = (unsigned char*)d_ws;
    int* best_last = (int*)((char*)d_ws + (size_t)BB * TT * KK);

    viterbi_fwd<<<BB, KK, 0, stream>>>(emissions, attn_mask, start_t, end_t,
                                       trans, hist, best_last);
    viterbi_bt<<<BB, 256, 0, stream>>>(hist, attn_mask, best_last, out);
}

// Round 4
// 517.458 us; speedup vs baseline: 2.2618x; 2.2618x over previous
//
#include <hip/hip_runtime.h>
#include <hip/hip_bf16.h>

// Viterbi CRF decode: B=512, T=512, K=64.
// Round 4: round-3 sync-free forward, but with the transition column FORCED
// into VGPRs: __launch_bounds__(64,1) lifts the 64-VGPR occupancy cap that
// made rounds 1/3 demote tc[64] to memory (VGPR_Count=64, phantom LDS +
// 2.2e7 bank conflicts, 1088us). tc lives in four ext_vector_type(16) SSA
// vectors (constant-index extractelement only); argmax state is named
// scalars. fp association (score+trans)+emit exact; 4 strict-> chains
// (ascending i) merged ascending = jnp.argmax first-index tie rule.
// Backtrace: round-3 hypothesis-parallel chase (unchanged).
// Workspace: hist uint8 [B][512][K] (row 511 pad) + best_last int[B].

#define TT 512
#define BB 512
#define KK 64

#define NEG_INF (-3.402823466e38f)

typedef float v16f __attribute__((ext_vector_type(16)));

__device__ __forceinline__ float rl(float v, int lane) {
    return __uint_as_float(__builtin_amdgcn_readlane(__float_as_uint(v), lane));
}

__global__ __launch_bounds__(64, 1) void viterbi_fwd(
    const float* __restrict__ emissions,   // [B,T,K]
    const int* __restrict__ attn_mask,     // [B,T]
    const float* __restrict__ start_t,     // [K]
    const float* __restrict__ end_t,       // [K]
    const float* __restrict__ trans,       // [K,K]
    unsigned char* __restrict__ hist,      // [B,512,K] (row 511 pad)
    int* __restrict__ best_last)           // [B]
{
    const int b = blockIdx.x;
    const int j = threadIdx.x;

    // trans column j in four 16-wide SSA vectors (constant-index access only)
    v16f tc0, tc1, tc2, tc3;
#pragma unroll
    for (int q = 0; q < 16; ++q) {
        tc0[q] = trans[(q)      * KK + j];
        tc1[q] = trans[(16 + q) * KK + j];
        tc2[q] = trans[(32 + q) * KK + j];
        tc3[q] = trans[(48 + q) * KK + j];
    }

    const float* eb = emissions + (size_t)b * TT * KK;
    const int*   mb = attn_mask + (size_t)b * TT;
    unsigned char* hb = hist + (size_t)b * TT * KK;

    float score = start_t[j] + eb[j];

    // 2-deep prefetch rings
    float e0 = eb[KK + j];
    float e1 = eb[2 * KK + j];
    int   m0 = mb[1];
    int   m1 = mb[2];

    for (int t = 1; t < TT; ++t) {
        float e = e0; e0 = e1;
        int   m = m0; m0 = m1;
        int tn = (t + 2 < TT) ? (t + 2) : (TT - 1);
        e1 = eb[(size_t)tn * KK + j];
        m1 = mb[tn];

        // 4 strict-> chains over ascending i, merged ascending:
        // reproduces jnp.argmax first-index tie-break exactly.
        float bv0 = NEG_INF, bv1 = NEG_INF, bv2 = NEG_INF, bv3 = NEG_INF;
        int   bi0 = 0, bi1 = 16, bi2 = 32, bi3 = 48;
#pragma unroll
        for (int q = 0; q < 16; ++q) {
            {
                float s = rl(score, q);
                float c = (s + tc0[q]) + e;      // exact reference association
                if (c > bv0) { bv0 = c; bi0 = q; }
            }
            {
                float s = rl(score, 16 + q);
                float c = (s + tc1[q]) + e;
                if (c > bv1) { bv1 = c; bi1 = 16 + q; }
            }
            {
                float s = rl(score, 32 + q);
                float c = (s + tc2[q]) + e;
                if (c > bv2) { bv2 = c; bi2 = 32 + q; }
            }
            {
                float s = rl(score, 48 + q);
                float c = (s + tc3[q]) + e;
                if (c > bv3) { bv3 = c; bi3 = 48 + q; }
            }
        }
        float best = bv0; int bi = bi0;
        if (bv1 > best) { best = bv1; bi = bi1; }
        if (bv2 > best) { best = bv2; bi = bi2; }
        if (bv3 > best) { best = bv3; bi = bi3; }

        hb[(size_t)(t - 1) * KK + j] = (unsigned char)bi;
        score = m ? best : score;   // freeze past sequence end
    }

    // final argmax (uniform on all lanes via readlane; lane 0 stores)
    float fin = score + end_t[j];
    float bv = rl(fin, 0); int bt_ = 0;
#pragma unroll
    for (int k = 1; k < KK; ++k) {
        float v = rl(fin, k);
        if (v > bv) { bv = v; bt_ = k; }
    }
    if (j == 0) best_last[b] = bt_;
}

__global__ __launch_bounds__(256) void viterbi_bt(
    const unsigned char* __restrict__ hist,  // [B,512,K]
    const int* __restrict__ attn_mask,       // [B,T]
    const int* __restrict__ best_last,       // [B]
    int* __restrict__ out)                   // [B,T] int32
{
    const int b   = blockIdx.x;
    const int tid = threadIdx.x;
    const int w   = __builtin_amdgcn_readfirstlane(tid >> 6);  // wave id
    const int l   = tid & 63;

    __shared__ unsigned char sh[TT * KK];    // 32 KB hist block
    __shared__ unsigned char maps[8][KK];    // chunk exit maps
    __shared__ int entries[8];

    // cooperative coalesced staging: 2048 uint4 over 256 lanes
    {
        const uint4* hw4 = (const uint4*)(hist + (size_t)b * TT * KK);
        uint4* sh4 = (uint4*)sh;
#pragma unroll
        for (int k = 0; k < 8; ++k) sh4[tid + k * 256] = hw4[tid + k * 256];
    }
    const int* mb = attn_mask + (size_t)b * TT;
    __syncthreads();

    // hypothesis-parallel chase: wave w handles chunks c = w, w+4.
    // lane l chases entry hypothesis tag=l through the chunk, recording the
    // path bytes packed 4-per-dword in registers.
    unsigned int rec_reg[2][16];
#pragma unroll
    for (int cc = 0; cc < 2; ++cc) {
        const int c = w + cc * 4;
        // mask bits for rows r = c*64 + i (row r uses attn_mask[b][r+1])
        int r_l = c * KK + l;
        int mreg = (r_l <= TT - 2) ? mb[r_l + 1] : 0;
        unsigned long long mb64 = __ballot(mreg != 0);

        int tag = l;
#pragma unroll
        for (int k = 0; k < 16; ++k) rec_reg[cc][k] = 0;
#pragma unroll
        for (int i = 63; i >= 0; --i) {
            // hist[r][tag], r = c*64+i (row 511 read is dead, mask bit = 0)
            int v = (int)sh[c * 4096 + i * KK + tag];
            int mbit = (int)((mb64 >> i) & 1ull);   // wave-uniform
            tag = mbit ? v : tag;
            rec_reg[cc][i >> 2] |= (unsigned int)tag << ((i & 3) * 8);
        }
        maps[c][l] = (unsigned char)tag;   // chunk exit for hypothesis l
    }
    __syncthreads();

    // compose the 8 chunk maps (serial, tiny)
    if (tid == 0) {
        int tg = best_last[b];
        for (int c = 7; c >= 0; --c) {
            entries[c] = tg;        // true entry tag for chunk c
            tg = maps[c][tg];       // exit becomes entry of chunk c-1
        }
    }
    __syncthreads();

    // emit: broadcast the winning lane's record via 16 uniform shuffles
#pragma unroll
    for (int cc = 0; cc < 2; ++cc) {
        const int c = w + cc * 4;
        const int e = entries[c];
        unsigned int myd = 0;
#pragma unroll
        for (int k = 0; k < 16; ++k) {
            unsigned int dv = (unsigned int)__shfl((int)rec_reg[cc][k], e);
            if ((l >> 2) == k) myd = dv;
        }
        int v = (int)((myd >> ((l & 3) * 8)) & 0xFFu);
        out[(size_t)b * TT + c * KK + l] = v;
    }
}

extern "C" void kernel_launch(void* const* d_in, const int* in_sizes, int n_in,
                              void* d_out, int out_size, void* d_ws, size_t ws_size,
                              hipStream_t stream) {
    const float* emissions = (const float*)d_in[0];
    const int* attn_mask   = (const int*)d_in[1];
    const float* start_t   = (const float*)d_in[2];
    const float* end_t     = (const float*)d_in[3];
    const float* trans     = (const float*)d_in[4];
    int* out = (int*)d_out;

    unsigned char* hist = (unsigned char*)d_ws;
    int* best_last = (int*)((char*)d_ws + (size_t)BB * TT * KK);

    viterbi_fwd<<<BB, KK, 0, stream>>>(emissions, attn_mask, start_t, end_t,
                                       trans, hist, best_last);
    viterbi_bt<<<BB, 256, 0, stream>>>(hist, attn_mask, best_last, out);
}